// Round 1
// 207.042 us; speedup vs baseline: 1.0953x; 1.0953x over previous
//
#include <hip/hip_runtime.h>
#include <hip/hip_bf16.h>
#include <math.h>

#define BB 4
#define CC 256
#define HH 128
#define WW 128
#define HWS (HH*WW)          // 16384
#define NHEADS 8
#define DD (HWS/NHEADS)      // 2048

typedef __attribute__((ext_vector_type(8))) short bf16x8;
typedef __attribute__((ext_vector_type(4))) float f32x4;
typedef __attribute__((ext_vector_type(2))) __fp16 h16x2;
typedef __attribute__((ext_vector_type(8))) __fp16 h16x8;

#define GLD_LDS(g, l) __builtin_amdgcn_global_load_lds( \
    (const __attribute__((address_space(1))) void*)(g),  \
    (__attribute__((address_space(3))) void*)(l), 16, 0, 0)

static __device__ __forceinline__ unsigned short f2bf(float f) {
    unsigned int u = __float_as_uint(f);
    unsigned int r = (u + 0x7FFFu + ((u >> 16) & 1u)) >> 16;
    return (unsigned short)r;
}
static __device__ __forceinline__ float b2f(unsigned short u) {
    return __uint_as_float((unsigned int)u << 16);
}
static __device__ __forceinline__ unsigned int pk2(float a, float b) {
    union { h16x2 h; unsigned int u; } x;
    x.h = __builtin_amdgcn_cvt_pkrtz(a, b);
    return x.u;
}
static __device__ __forceinline__ h16x2 u2h(unsigned int u) {
    union { unsigned int u; h16x2 h; } x;
    x.u = u;
    return x.h;
}

// ---------------- PE table ----------------
__global__ __launch_bounds__(256) void pe_kernel(float* __restrict__ pe)
{
    const int c = blockIdx.x;
    const float coef = -1.1243088e-3f;   // -ln(10000)/8192
    float* row = pe + (size_t)c * HWS;
    for (int j = threadIdx.x; j < HWS / 2; j += 256) {
        float sv, cv;
        sincosf((float)c * expf(coef * (float)j), &sv, &cv);
        *(float2*)(row + 2 * j) = make_float2(sv, cv);
    }
}

// -------- weight pack: w[c][81] f32 -> wp[c][9][5] half2 (tap pairs) -- used by conv9o --------
__global__ __launch_bounds__(64) void wpack(
    const float* __restrict__ w0, unsigned int* __restrict__ d0,
    const float* __restrict__ w1, unsigned int* __restrict__ d1,
    const float* __restrict__ w2, unsigned int* __restrict__ d2,
    const float* __restrict__ w3, unsigned int* __restrict__ d3)
{
    const int c = blockIdx.x;
    const int a = blockIdx.y;
    const float* w = (a == 0) ? w0 : (a == 1) ? w1 : (a == 2) ? w2 : w3;
    unsigned int* d = (a == 0) ? d0 : (a == 1) ? d1 : (a == 2) ? d2 : d3;
    const int t = threadIdx.x;
    if (t < 45) {
        const int ky = t / 5, kp = t - ky * 5, kx = kp << 1;
        const float va = w[c * 81 + ky * 9 + kx];
        const float vb = (kx + 1 < 9) ? w[c * 81 + ky * 9 + kx + 1] : 0.0f;
        d[(c * 9 + ky) * 5 + kp] = pk2(va, vb);
    }
}

// ---- Toeplitz B-fragment tables for MFMA conv: wt[cv][c][ky][lane][8] f16 ----
// B[k][n] = w[c][ky][k-n] for 0<=k-n<=8 else 0; lane: n=lane&15, k=(lane>>4)*8+e
__global__ __launch_bounds__(256) void build_wt(
    const float* __restrict__ qw, const float* __restrict__ kw,
    const float* __restrict__ vw, unsigned short* __restrict__ wt)
{
    const int c = blockIdx.x, cv = blockIdx.y;
    const float* w = (cv == 0) ? qw : (cv == 1) ? kw : vw;
    unsigned short* dst = wt + ((size_t)(cv * CC + c) * 9) * 512;
    for (int idx = threadIdx.x; idx < 9 * 512; idx += 256) {
        const int ky   = idx >> 9;
        const int rem  = idx & 511;
        const int lane = rem >> 3, e = rem & 7;
        const int n = lane & 15;
        const int k = ((lane >> 4) << 3) + e;
        const int d = k - n;
        const float v = (d >= 0 && d <= 8) ? w[c * 81 + ky * 9 + d] : 0.0f;
        const __fp16 hv = (__fp16)v;
        unsigned short bits;
        __builtin_memcpy(&bits, &hv, 2);
        dst[idx] = bits;
    }
}

// ---- shared conv inner for conv9o: f16 dot2 over kx-pairs ----
#define MAKE_WIN(tileref, rowi)                                          \
    const float4 F0 = *(const float4*)&tileref[rowi][ox];                \
    const float4 F1 = *(const float4*)&tileref[rowi][ox + 4];            \
    const float4 F2 = *(const float4*)&tileref[rowi][ox + 8];            \
    const float2 F3 = *(const float2*)&tileref[rowi][ox + 12];           \
    unsigned int P[7], O[6];                                             \
    P[0] = pk2(F0.x, F0.y); P[1] = pk2(F0.z, F0.w);                      \
    P[2] = pk2(F1.x, F1.y); P[3] = pk2(F1.z, F1.w);                      \
    P[4] = pk2(F2.x, F2.y); P[5] = pk2(F2.z, F2.w);                      \
    P[6] = pk2(F3.x, F3.y);                                              \
    _Pragma("unroll")                                                    \
    for (int ii = 0; ii < 6; ++ii)                                       \
        O[ii] = __builtin_amdgcn_alignbit(P[ii + 1], P[ii], 16);

#define WINP(s) (((s) & 1) ? O[(s) >> 1] : P[(s) >> 1])

// ------- fused QKV depthwise 9x9 conv — MFMA (x-axis Toeplitz) version -------
// Per block: one 64x64 region of one (b,c) plane. 4 waves; wave wr owns 16 rows x 64 cols.
// LDS: f16 input tile [72 rows][80 cols] (XOR-swizzled), + 27 Toeplitz B-frags (1KB each).
#define TILE_BYTES 11520           // 72 * 160
#define AWB_OFF    TILE_BYTES      // 27 * 1024 = 27648
__global__ __launch_bounds__(256, 4) void conv9qkv(
    const float* __restrict__ in, const float* __restrict__ pe,
    const unsigned short* __restrict__ wt,
    const float* __restrict__ b0, const float* __restrict__ b1,
    const float* __restrict__ b2,
    unsigned short* __restrict__ o0, unsigned short* __restrict__ o1,
    unsigned short* __restrict__ o2)
{
    __shared__ alignas(16) char lds[TILE_BYTES + 27648];   // 39168 B -> 4 blocks/CU

    const int bid   = blockIdx.x;
    const int t     = bid & 3;
    const int plane = bid >> 2;
    const int c     = plane & (CC - 1);
    const int bidx  = plane >> 8;
    const int tr    = (t >> 1) << 6;
    const int tc    = (t & 1) << 6;
    const int tid   = threadIdx.x;
    const int lane  = tid & 63;
    const int wr    = tid >> 6;
    const int r16   = lane & 15;
    const int g     = lane >> 4;

    // ---- issue async staging of the 27 Toeplitz fragments (linear lane*16 layout) ----
    for (int f = wr; f < 27; f += 4) {
        const int cv = f / 9;
        const int ky = f - cv * 9;
        const char* src = (const char*)wt
            + ((((size_t)cv * CC + c) * 9 + ky) << 10) + (lane << 4);
        GLD_LDS(src, lds + AWB_OFF + (f << 10) + (lane << 4));
    }

    const float* xp  = in + (size_t)plane * HWS;
    const float* pep = pe + (size_t)c * HWS;

    // ---- stage 72x80 halo tile (x + pe) as f16, XOR-swizzled: byte ^= (row&7)<<4 ----
    for (int i = tid; i < 72 * 20; i += 256) {
        const int row = i / 20;
        const int c4  = i - row * 20;
        const int gy  = tr + row - 4;
        const int gx  = tc + (c4 << 2) - 4;
        float4 val = make_float4(0.f, 0.f, 0.f, 0.f);
        if (gy >= 0 && gy < HH) {
            if (gx >= 0 && gx + 3 < WW) {
                val = *(const float4*)(xp + gy * WW + gx);
                const float4 p = *(const float4*)(pep + gy * WW + gx);
                val.x += p.x; val.y += p.y; val.z += p.z; val.w += p.w;
            } else {
                float* vv = (float*)&val;
                #pragma unroll
                for (int e = 0; e < 4; ++e) {
                    const int gxe = gx + e;
                    if (gxe >= 0 && gxe < WW)
                        vv[e] = xp[gy * WW + gxe] + pep[gy * WW + gxe];
                }
            }
        }
        const unsigned int lo = pk2(val.x, val.y);
        const unsigned int hi = pk2(val.z, val.w);
        int byte = row * 160 + (c4 << 3);
        byte ^= (row & 7) << 4;
        *(uint2*)(lds + byte) = make_uint2(lo, hi);
    }
    __syncthreads();

    // ---- MFMA main: D[m=y][n=x] += A(input)[m][k=x'] * B(Toeplitz)[k][n], per ky ----
    f32x4 acc[3][4];
    {
        const float bq = b0[c], bk = b1[c], bv = b2[c];
        #pragma unroll
        for (int xt = 0; xt < 4; ++xt) {
            acc[0][xt] = (f32x4){bq, bq, bq, bq};
            acc[1][xt] = (f32x4){bk, bk, bk, bk};
            acc[2][xt] = (f32x4){bv, bv, bv, bv};
        }
    }

    const int rowbase = (wr << 4) + r16;
    for (int ky = 0; ky < 9; ++ky) {
        const int row = rowbase + ky;
        const int sx  = (row & 7) << 4;
        const int rb  = row * 160 + (g << 4);
        h16x8 a[4];
        #pragma unroll
        for (int xt = 0; xt < 4; ++xt)
            a[xt] = *(const h16x8*)(lds + ((rb + (xt << 5)) ^ sx));
        #pragma unroll
        for (int cv = 0; cv < 3; ++cv) {
            const h16x8 bfrag = *(const h16x8*)(lds + AWB_OFF + ((cv * 9 + ky) << 10) + (lane << 4));
            #pragma unroll
            for (int xt = 0; xt < 4; ++xt)
                acc[cv][xt] = __builtin_amdgcn_mfma_f32_16x16x32_f16(
                    a[xt], bfrag, acc[cv][xt], 0, 0, 0);
        }
    }

    // ---- epilogue: bounce through LDS (reusing tile area) for coalesced 16B stores ----
    __syncthreads();
    unsigned short* const outs[3] = { o0, o1, o2 };
    const int ybase = tr + (wr << 4);
    #pragma unroll
    for (int cv = 0; cv < 3; ++cv) {
        #pragma unroll
        for (int xt = 0; xt < 4; ++xt) {
            #pragma unroll
            for (int j = 0; j < 4; ++j) {
                const int yloc = (g << 2) + j;
                int byte = (wr << 11) + (yloc << 7) + (((xt << 4) + r16) << 1);
                byte ^= (yloc & 7) << 4;
                *(unsigned short*)(lds + byte) = f2bf(acc[cv][xt][j]);
            }
        }
        __syncthreads();
        #pragma unroll
        for (int r = 0; r < 2; ++r) {
            const int flat = (r << 9) + (lane << 3);   // bf16 units within wave region
            const int yloc = flat >> 6;
            int byte = (wr << 11) + (flat << 1);
            byte ^= (yloc & 7) << 4;
            const bf16x8 vv = *(const bf16x8*)(lds + byte);
            const int y = ybase + yloc;
            const int h = y >> 4;
            const size_t off = (((size_t)(bidx * NHEADS + h) * CC + c) << 11)
                             + ((size_t)(y & 15) << 7) + tc + (flat & 63);
            *(bf16x8*)(outs[cv] + off) = vv;
        }
        __syncthreads();
    }
}

// ------- output depthwise 9x9 conv: bf16 input, dot2 inner math (unchanged) -------
__global__ __launch_bounds__(256, 4) void conv9o(
    const unsigned short* __restrict__ ain,
    const unsigned int* __restrict__ wpo, const float* __restrict__ b,
    float* __restrict__ out)
{
    __shared__ float tile[72][76];

    const int bid   = blockIdx.x;
    const int t     = bid & 3;
    const int plane = bid >> 2;
    const int c     = plane & (CC - 1);
    const int tr    = (t >> 1) << 6;
    const int tc    = (t & 1) << 6;
    const int tid   = threadIdx.x;

    const unsigned short* ap = ain + (size_t)plane * HWS;

    for (int i = tid; i < 72 * 19; i += 256) {
        const int row = i / 19;
        const int c4  = i - row * 19;
        const int gy  = tr + row - 4;
        const int gx  = tc + (c4 << 2) - 4;
        float4 val = make_float4(0.f, 0.f, 0.f, 0.f);
        if (gy >= 0 && gy < HH) {
            if (gx >= 0 && gx + 3 < WW) {
                const ushort4 u = *(const ushort4*)(ap + gy * WW + gx);
                val.x = b2f(u.x); val.y = b2f(u.y); val.z = b2f(u.z); val.w = b2f(u.w);
            } else {
                float* vv = (float*)&val;
                #pragma unroll
                for (int e = 0; e < 4; ++e) {
                    const int gxe = gx + e;
                    if (gxe >= 0 && gxe < WW)
                        vv[e] = b2f(ap[gy * WW + gxe]);
                }
            }
        }
        *(float4*)&tile[row][c4 << 2] = val;
    }
    __syncthreads();

    const int txq = tid & 15;
    const int tyq = tid >> 4;
    const int ox  = txq << 2;
    const int oy  = tyq << 2;

    const unsigned int* wc = wpo + c * 45;
    const float bv = b[c];

    float acc[4][4];
    #pragma unroll
    for (int r = 0; r < 4; ++r)
        #pragma unroll
        for (int j = 0; j < 4; ++j)
            acc[r][j] = bv;

    for (int m = 0; m < 12; ++m) {
        MAKE_WIN(tile, oy + m)
        #pragma unroll
        for (int r = 0; r < 4; ++r) {
            const int ky = m - r;
            if (ky >= 0 && ky <= 8) {
                const unsigned int* wrow = wc + ky * 5;
                #pragma unroll
                for (int kp = 0; kp < 5; ++kp) {
                    const h16x2 wv = u2h(wrow[kp]);
                    #pragma unroll
                    for (int j = 0; j < 4; ++j)
                        acc[r][j] = __builtin_amdgcn_fdot2(
                            u2h(WINP(2 * kp + j)), wv, acc[r][j], false);
                }
            }
        }
    }

    #pragma unroll
    for (int r = 0; r < 4; ++r) {
        const int y = tr + oy + r;
        float4 o;
        o.x = acc[r][0]; o.y = acc[r][1]; o.z = acc[r][2]; o.w = acc[r][3];
        *(float4*)(out + (size_t)plane * HWS + (size_t)y * WW + (tc + ox)) = o;
    }
}

// ------------- V transpose per (b,h): vT[d][c] = v[c][d] -------------
__global__ __launch_bounds__(256) void transpose_v(
    const unsigned short* __restrict__ v, unsigned short* __restrict__ vT)
{
    __shared__ unsigned short t[64][72];

    const int bh = blockIdx.z;
    const int c0 = blockIdx.y << 6;
    const int d0 = blockIdx.x << 6;
    const int tid = threadIdx.x;
    const int r  = tid >> 2;
    const int q4 = tid & 3;

    const unsigned short* src = v + (size_t)bh * CC * DD + (size_t)(c0 + r) * DD + d0 + q4 * 16;
    bf16x8 v0 = *(const bf16x8*)(src);
    bf16x8 v1 = *(const bf16x8*)(src + 8);
    #pragma unroll
    for (int e = 0; e < 8; ++e) {
        t[q4 * 16 + e][r]     = (unsigned short)v0[e];
        t[q4 * 16 + 8 + e][r] = (unsigned short)v1[e];
    }
    __syncthreads();

    unsigned short* dst = vT + (size_t)bh * DD * CC + (size_t)(d0 + r) * CC + c0 + q4 * 16;
    *(bf16x8*)dst       = *(const bf16x8*)&t[r][q4 * 16];
    *(bf16x8*)(dst + 8) = *(const bf16x8*)&t[r][q4 * 16 + 8];
}

// ------------- bf16 MFMA GEMM (unchanged) -------------
template<bool IS_QK>
__global__ __launch_bounds__(256) void gemm_bf16(
    const unsigned short* __restrict__ Abuf, const unsigned short* __restrict__ Bbuf,
    void* __restrict__ Dout)
{
    constexpr int KT = IS_QK ? 2048 : 256;
    constexpr int NB = IS_QK ? 256 : 2048;

    __shared__ char lds[24576];

    const int tid = threadIdx.x;
    const int bh  = blockIdx.z;
    const int m0  = blockIdx.y << 7;
    const int n0  = blockIdx.x << 6;

    const unsigned short* Ab = Abuf + (size_t)bh * CC * KT + (size_t)m0 * KT;
    const unsigned short* Bb = Bbuf + (size_t)bh * NB * KT + (size_t)n0 * KT;

    const int lane = tid & 63;
    const int w    = tid >> 6;
    const int wm   = (w >> 1) << 6;
    const int wn   = (w & 1) << 5;
    const int r16  = lane & 15;
    const int g    = lane >> 4;

    const int trow = tid >> 3;
    const int slot = tid & 7;

    f32x4 acc[4][2] = {};

    for (int kt = 0; kt < KT / 64; ++kt) {
        const int kc = kt << 6;
        #pragma unroll
        for (int i = 0; i < 4; ++i) {
            const int row = (i << 5) + trow;
            const int gs  = slot ^ (row & 7);
            const char* srcp = (const char*)(Ab + (size_t)row * KT + kc) + gs * 16;
            GLD_LDS(srcp, lds + (i << 12) + tid * 16);
        }
        #pragma unroll
        for (int i = 0; i < 2; ++i) {
            const int row = (i << 5) + trow;
            const int gs  = slot ^ (row & 7);
            const char* srcp = (const char*)(Bb + (size_t)row * KT + kc) + gs * 16;
            GLD_LDS(srcp, lds + 16384 + (i << 12) + tid * 16);
        }
        __syncthreads();
        #pragma unroll
        for (int kk = 0; kk < 2; ++kk) {
            bf16x8 af[4], bfr[2];
            #pragma unroll
            for (int mi = 0; mi < 4; ++mi) {
                const int row = wm + (mi << 4) + r16;
                af[mi] = *(const bf16x8*)(lds + row * 128 + ((((kk << 2) + g) ^ (row & 7)) << 4));
            }
            #pragma unroll
            for (int nj = 0; nj < 2; ++nj) {
                const int row = wn + (nj << 4) + r16;
                bfr[nj] = *(const bf16x8*)(lds + 16384 + row * 128 + ((((kk << 2) + g) ^ (row & 7)) << 4));
            }
            #pragma unroll
            for (int mi = 0; mi < 4; ++mi)
                #pragma unroll
                for (int nj = 0; nj < 2; ++nj)
                    acc[mi][nj] = __builtin_amdgcn_mfma_f32_16x16x32_bf16(af[mi], bfr[nj], acc[mi][nj], 0, 0, 0);
        }
        __syncthreads();
    }

    if (IS_QK) {
        float* sp = (float*)Dout + (size_t)bh * 65536;
        #pragma unroll
        for (int mi = 0; mi < 4; ++mi)
            #pragma unroll
            for (int nj = 0; nj < 2; ++nj)
                #pragma unroll
                for (int j = 0; j < 4; ++j) {
                    const int row = m0 + wm + (mi << 4) + (g << 2) + j;
                    const int col = n0 + wn + (nj << 4) + r16;
                    sp[(size_t)row * 256 + col] = acc[mi][nj][j] * 0.0078125f;
                }
    } else {
        unsigned short* Ao = (unsigned short*)Dout;
        const int b = bh >> 3, h = bh & 7;
        #pragma unroll
        for (int mi = 0; mi < 4; ++mi)
            #pragma unroll
            for (int nj = 0; nj < 2; ++nj)
                #pragma unroll
                for (int j = 0; j < 4; ++j) {
                    const int row = m0 + wm + (mi << 4) + (g << 2) + j;
                    const int col = n0 + wn + (nj << 4) + r16;
                    Ao[((size_t)b * CC + row) * HWS + h * DD + col] = f2bf(acc[mi][nj][j]);
                }
    }
}

// ------------- row softmax: S fp32 -> P bf16 (unchanged) -------------
__global__ __launch_bounds__(256) void softmax_kernel(
    const float* __restrict__ S, __hip_bfloat16* __restrict__ P)
{
    __shared__ float redm[4], reds[4];
    const int row = blockIdx.x;
    const float* p = S + (size_t)row * 256;
    const int tid = threadIdx.x;
    float vv = p[tid];
    float m = vv;
    #pragma unroll
    for (int o = 32; o; o >>= 1) m = fmaxf(m, __shfl_xor(m, o, 64));
    if ((tid & 63) == 0) redm[tid >> 6] = m;
    __syncthreads();
    m = fmaxf(fmaxf(redm[0], redm[1]), fmaxf(redm[2], redm[3]));
    const float e = expf(vv - m);
    float s = e;
    #pragma unroll
    for (int o = 32; o; o >>= 1) s += __shfl_xor(s, o, 64);
    if ((tid & 63) == 0) reds[tid >> 6] = s;
    __syncthreads();
    s = reds[0] + reds[1] + reds[2] + reds[3];
    P[(size_t)row * 256 + tid] = __float2bfloat16(e / s);
}

extern "C" void kernel_launch(void* const* d_in, const int* in_sizes, int n_in,
                              void* d_out, int out_size, void* d_ws, size_t ws_size,
                              hipStream_t stream)
{
    const float* x  = (const float*)d_in[0];
    const float* qw = (const float*)d_in[1];
    const float* qb = (const float*)d_in[2];
    const float* kw = (const float*)d_in[3];
    const float* kb = (const float*)d_in[4];
    const float* vw = (const float*)d_in[5];
    const float* vb = (const float*)d_in[6];
    const float* ow = (const float*)d_in[7];
    const float* ob = (const float*)d_in[8];
    float* out = (float*)d_out;

    char* wsb = (char*)d_ws;
    float*          pe  = (float*)(wsb + 0);
    __hip_bfloat16* q   = (__hip_bfloat16*)(wsb + 16777216UL);
    __hip_bfloat16* k   = (__hip_bfloat16*)(wsb + 50331648UL);
    float*          S   = (float*)(wsb + 83886080UL);
    __hip_bfloat16* P   = (__hip_bfloat16*)(wsb + 92274688UL);
    __hip_bfloat16* v   = (__hip_bfloat16*)(wsb + 96468992UL);
    __hip_bfloat16* vT  = (__hip_bfloat16*)(wsb + 130023424UL);
    unsigned short* A   = (unsigned short*)(wsb + 0);   // aliases pe+q-half (dead by then)
    // Toeplitz f16 tables alias S (7.08 MB <= 8 MB): dead once conv9qkv completes,
    // before gemm<QK> writes S (stream-ordered).
    unsigned short* wt  = (unsigned short*)(wsb + 83886080UL);
    unsigned int*   wpo = (unsigned int*)(wsb + 163577856UL);            // 256*45*4 = 46080 B

    pe_kernel<<<dim3(CC), 256, 0, stream>>>(pe);
    wpack<<<dim3(CC, 1), 64, 0, stream>>>(ow, wpo, ow, wpo, ow, wpo, ow, wpo);
    build_wt<<<dim3(CC, 3), 256, 0, stream>>>(qw, kw, vw, wt);
    conv9qkv<<<dim3(BB * CC * 4), 256, 0, stream>>>(
        x, pe, wt, qb, kb, vb,
        (unsigned short*)q, (unsigned short*)k, (unsigned short*)v);
    gemm_bf16<true><<<dim3(4, 2, 32), 256, 0, stream>>>(
        (const unsigned short*)q, (const unsigned short*)k, (void*)S);
    softmax_kernel<<<dim3(32 * 256), 256, 0, stream>>>(S, P);
    transpose_v<<<dim3(DD / 64, CC / 64, 32), 256, 0, stream>>>(
        (const unsigned short*)v, (unsigned short*)vT);
    gemm_bf16<false><<<dim3(32, 2, 32), 256, 0, stream>>>(
        (const unsigned short*)P, (const unsigned short*)vT, (void*)A);
    conv9o<<<dim3(BB * CC * 4), 256, 0, stream>>>(A, wpo, ob, out);
}

// Round 2
// 191.890 us; speedup vs baseline: 1.1818x; 1.0790x over previous
//
#include <hip/hip_runtime.h>
#include <hip/hip_bf16.h>
#include <math.h>

#define BB 4
#define CC 256
#define HH 128
#define WW 128
#define HWS (HH*WW)          // 16384
#define NHEADS 8
#define DD (HWS/NHEADS)      // 2048

typedef __attribute__((ext_vector_type(8))) short bf16x8;
typedef __attribute__((ext_vector_type(4))) float f32x4;
typedef __attribute__((ext_vector_type(2))) __fp16 h16x2;
typedef __attribute__((ext_vector_type(8))) __fp16 h16x8;

#define GLD_LDS(g, l) __builtin_amdgcn_global_load_lds( \
    (const __attribute__((address_space(1))) void*)(g),  \
    (__attribute__((address_space(3))) void*)(l), 16, 0, 0)

static __device__ __forceinline__ unsigned short f2bf(float f) {
    unsigned int u = __float_as_uint(f);
    unsigned int r = (u + 0x7FFFu + ((u >> 16) & 1u)) >> 16;
    return (unsigned short)r;
}
static __device__ __forceinline__ float b2f(unsigned short u) {
    return __uint_as_float((unsigned int)u << 16);
}
static __device__ __forceinline__ unsigned int pk2(float a, float b) {
    union { h16x2 h; unsigned int u; } x;
    x.h = __builtin_amdgcn_cvt_pkrtz(a, b);
    return x.u;
}

// ---------------- PE table (fast HW sincos, 4 slabs per channel) ----------------
__global__ __launch_bounds__(256) void pe_kernel(float* __restrict__ pe)
{
    const int c  = blockIdx.x;
    const int jb = blockIdx.y;
    const float coef = -1.1243088e-3f;   // -ln(10000)/8192
    float* row = pe + (size_t)c * HWS;
    const int jend = (jb + 1) << 11;
    for (int j = (jb << 11) + threadIdx.x; j < jend; j += 256) {
        float sv, cv;
        __sincosf((float)c * __expf(coef * (float)j), &sv, &cv);
        *(float2*)(row + 2 * j) = make_float2(sv, cv);
    }
}

// ---- Toeplitz B-fragment tables for MFMA conv: wt[cv][c][ky][lane][8] f16 ----
// B[k][n] = w[c][ky][k-n] for 0<=k-n<=8 else 0; lane: n=lane&15, k=(lane>>4)*8+e
__global__ __launch_bounds__(256) void build_wt(
    const float* __restrict__ qw, const float* __restrict__ kw,
    const float* __restrict__ vw, unsigned short* __restrict__ wt)
{
    const int c = blockIdx.x, cv = blockIdx.y;
    const float* w = (cv == 0) ? qw : (cv == 1) ? kw : vw;
    unsigned short* dst = wt + ((size_t)(cv * CC + c) * 9) * 512;
    for (int idx = threadIdx.x; idx < 9 * 512; idx += 256) {
        const int ky   = idx >> 9;
        const int rem  = idx & 511;
        const int lane = rem >> 3, e = rem & 7;
        const int n = lane & 15;
        const int k = ((lane >> 4) << 3) + e;
        const int d = k - n;
        const float v = (d >= 0 && d <= 8) ? w[c * 81 + ky * 9 + d] : 0.0f;
        const __fp16 hv = (__fp16)v;
        unsigned short bits;
        __builtin_memcpy(&bits, &hv, 2);
        dst[idx] = bits;
    }
}

// XCD-chunked c-major swizzle: 4096 blocks, 8 XCDs -> each XCD owns 32 channels;
// all 16 blocks (4 batch x 4 tiles) of a channel are contiguous on one XCD.
static __device__ __forceinline__ void decode_bid(int bid, int& c, int& bidx, int& t) {
    const int u = (bid & 7) * 512 + (bid >> 3);
    c = u >> 4; bidx = (u >> 2) & 3; t = u & 3;
}

// ------- fused QKV depthwise 9x9 conv — MFMA (x-axis Toeplitz) -------
#define TILE_BYTES 11520           // 72 * 160
#define AWB_OFF    TILE_BYTES      // 27 * 1024 = 27648
__global__ __launch_bounds__(256, 4) void conv9qkv(
    const float* __restrict__ in, const float* __restrict__ pe,
    const unsigned short* __restrict__ wt,
    const float* __restrict__ b0, const float* __restrict__ b1,
    const float* __restrict__ b2,
    unsigned short* __restrict__ o0, unsigned short* __restrict__ o1,
    unsigned short* __restrict__ o2)
{
    __shared__ alignas(16) char lds[TILE_BYTES + 27648];   // 39168 B -> 4 blocks/CU

    int c, bidx, t;
    decode_bid(blockIdx.x, c, bidx, t);
    const int plane = bidx * CC + c;
    const int tr    = (t >> 1) << 6;
    const int tc    = (t & 1) << 6;
    const int tid   = threadIdx.x;
    const int lane  = tid & 63;
    const int wr    = tid >> 6;
    const int r16   = lane & 15;
    const int g     = lane >> 4;

    // ---- issue async staging of the 27 Toeplitz fragments (linear lane*16 layout) ----
    for (int f = wr; f < 27; f += 4) {
        const int cv = f / 9;
        const int ky = f - cv * 9;
        const char* src = (const char*)wt
            + ((((size_t)cv * CC + c) * 9 + ky) << 10) + (lane << 4);
        GLD_LDS(src, lds + AWB_OFF + (f << 10) + (lane << 4));
    }

    const float* xp  = in + (size_t)plane * HWS;
    const float* pep = pe + (size_t)c * HWS;

    // ---- stage 72x80 halo tile (x + pe) as f16, XOR-swizzled, 8 px / item ----
    #pragma unroll
    for (int it = 0; it < 3; ++it) {
        const int i = tid + (it << 8);
        if (i < 720) {
            const int row = i / 10;
            const int c8  = i - row * 10;
            const int gy  = tr + row - 4;
            const int gx  = tc + (c8 << 3) - 4;
            uint4 wv = make_uint4(0u, 0u, 0u, 0u);
            if (gy >= 0 && gy < HH) {
                const float* xr = xp + gy * WW;
                const float* pr = pep + gy * WW;
                if (gx >= 0 && gx + 7 < WW) {
                    const float4 a0 = *(const float4*)(xr + gx);
                    const float4 a1 = *(const float4*)(xr + gx + 4);
                    const float4 p0 = *(const float4*)(pr + gx);
                    const float4 p1 = *(const float4*)(pr + gx + 4);
                    wv.x = pk2(a0.x + p0.x, a0.y + p0.y);
                    wv.y = pk2(a0.z + p0.z, a0.w + p0.w);
                    wv.z = pk2(a1.x + p1.x, a1.y + p1.y);
                    wv.w = pk2(a1.z + p1.z, a1.w + p1.w);
                } else {
                    float vv[8];
                    #pragma unroll
                    for (int e = 0; e < 8; ++e) {
                        const int gxe = gx + e;
                        vv[e] = (gxe >= 0 && gxe < WW) ? (xr[gxe] + pr[gxe]) : 0.f;
                    }
                    wv.x = pk2(vv[0], vv[1]); wv.y = pk2(vv[2], vv[3]);
                    wv.z = pk2(vv[4], vv[5]); wv.w = pk2(vv[6], vv[7]);
                }
            }
            int byte = row * 160 + (c8 << 4);
            byte ^= (row & 7) << 4;
            *(uint4*)(lds + byte) = wv;
        }
    }
    __syncthreads();

    // ---- MFMA main: D[m=y][n=x] += A(input)[m][k=x'] * B(Toeplitz)[k][n], per ky ----
    f32x4 acc[3][4];
    {
        const float bq = b0[c], bk = b1[c], bv = b2[c];
        #pragma unroll
        for (int xt = 0; xt < 4; ++xt) {
            acc[0][xt] = (f32x4){bq, bq, bq, bq};
            acc[1][xt] = (f32x4){bk, bk, bk, bk};
            acc[2][xt] = (f32x4){bv, bv, bv, bv};
        }
    }

    const int rowbase = (wr << 4) + r16;
    for (int ky = 0; ky < 9; ++ky) {
        const int row = rowbase + ky;
        const int sx  = (row & 7) << 4;
        const int rb  = row * 160 + (g << 4);
        h16x8 a[4];
        #pragma unroll
        for (int xt = 0; xt < 4; ++xt)
            a[xt] = *(const h16x8*)(lds + ((rb + (xt << 5)) ^ sx));
        #pragma unroll
        for (int cv = 0; cv < 3; ++cv) {
            const h16x8 bfrag = *(const h16x8*)(lds + AWB_OFF + ((cv * 9 + ky) << 10) + (lane << 4));
            #pragma unroll
            for (int xt = 0; xt < 4; ++xt)
                acc[cv][xt] = __builtin_amdgcn_mfma_f32_16x16x32_f16(
                    a[xt], bfrag, acc[cv][xt], 0, 0, 0);
        }
    }

    // ---- epilogue: bounce through LDS (reusing tile area) for coalesced 16B stores ----
    __syncthreads();
    unsigned short* const outs[3] = { o0, o1, o2 };
    const int ybase = tr + (wr << 4);
    #pragma unroll
    for (int cv = 0; cv < 3; ++cv) {
        #pragma unroll
        for (int xt = 0; xt < 4; ++xt) {
            #pragma unroll
            for (int j = 0; j < 4; ++j) {
                const int yloc = (g << 2) + j;
                int byte = (wr << 11) + (yloc << 7) + (((xt << 4) + r16) << 1);
                byte ^= (yloc & 7) << 4;
                *(unsigned short*)(lds + byte) = f2bf(acc[cv][xt][j]);
            }
        }
        __syncthreads();
        #pragma unroll
        for (int r = 0; r < 2; ++r) {
            const int flat = (r << 9) + (lane << 3);   // bf16 units within wave region
            const int yloc = flat >> 6;
            int byte = (wr << 11) + (flat << 1);
            byte ^= (yloc & 7) << 4;
            const bf16x8 vv = *(const bf16x8*)(lds + byte);
            const int y = ybase + yloc;
            const int h = y >> 4;
            const size_t off = (((size_t)(bidx * NHEADS + h) * CC + c) << 11)
                             + ((size_t)(y & 15) << 7) + tc + (flat & 63);
            *(bf16x8*)(outs[cv] + off) = vv;
        }
        __syncthreads();
    }
}

// ------- output depthwise 9x9 conv: bf16 input, MFMA Toeplitz, in-kernel frag build -------
#define O_FRAG_OFF 11520           // 9 * 1024 = 9216 bytes of fragments
__global__ __launch_bounds__(256, 4) void conv9o(
    const unsigned short* __restrict__ ain,
    const float* __restrict__ w, const float* __restrict__ b,
    float* __restrict__ out)
{
    __shared__ alignas(16) char lds[O_FRAG_OFF + 9216];
    __shared__ float lw[81];

    int c, bidx, t;
    decode_bid(blockIdx.x, c, bidx, t);
    const int plane = bidx * CC + c;
    const int tr    = (t >> 1) << 6;
    const int tc    = (t & 1) << 6;
    const int tid   = threadIdx.x;
    const int lane  = tid & 63;
    const int wr    = tid >> 6;
    const int r16   = lane & 15;
    const int g     = lane >> 4;

    if (tid < 81) lw[tid] = w[c * 81 + tid];

    const unsigned short* ap = ain + (size_t)plane * HWS;

    // ---- stage 72x80 halo tile as f16, XOR-swizzled, 8 px / item ----
    #pragma unroll
    for (int it = 0; it < 3; ++it) {
        const int i = tid + (it << 8);
        if (i < 720) {
            const int row = i / 10;
            const int c8  = i - row * 10;
            const int gy  = tr + row - 4;
            const int gx  = tc + (c8 << 3) - 4;
            uint4 wv = make_uint4(0u, 0u, 0u, 0u);
            if (gy >= 0 && gy < HH) {
                const unsigned short* ar = ap + gy * WW;
                if (gx >= 0 && gx + 7 < WW) {
                    const bf16x8 u = *(const bf16x8*)(ar + gx);
                    wv.x = pk2(b2f((unsigned short)u[0]), b2f((unsigned short)u[1]));
                    wv.y = pk2(b2f((unsigned short)u[2]), b2f((unsigned short)u[3]));
                    wv.z = pk2(b2f((unsigned short)u[4]), b2f((unsigned short)u[5]));
                    wv.w = pk2(b2f((unsigned short)u[6]), b2f((unsigned short)u[7]));
                } else {
                    float vv[8];
                    #pragma unroll
                    for (int e = 0; e < 8; ++e) {
                        const int gxe = gx + e;
                        vv[e] = (gxe >= 0 && gxe < WW) ? b2f(ar[gxe]) : 0.f;
                    }
                    wv.x = pk2(vv[0], vv[1]); wv.y = pk2(vv[2], vv[3]);
                    wv.z = pk2(vv[4], vv[5]); wv.w = pk2(vv[6], vv[7]);
                }
            }
            int byte = row * 160 + (c8 << 4);
            byte ^= (row & 7) << 4;
            *(uint4*)(lds + byte) = wv;
        }
    }
    __syncthreads();

    // ---- build the 9 Toeplitz B-fragments in LDS from lw (u32 = f16 pair per write) ----
    {
        const int ln = tid >> 2, qq = tid & 3;
        const int n  = ln & 15;
        const int k0 = ((ln >> 4) << 3) + (qq << 1);
        const int d0 = k0 - n, d1 = k0 + 1 - n;
        #pragma unroll
        for (int ky = 0; ky < 9; ++ky) {
            const float f0 = (d0 >= 0 && d0 <= 8) ? lw[ky * 9 + d0] : 0.f;
            const float f1 = (d1 >= 0 && d1 <= 8) ? lw[ky * 9 + d1] : 0.f;
            *(unsigned int*)(lds + O_FRAG_OFF + (ky << 10) + (ln << 4) + (qq << 2)) = pk2(f0, f1);
        }
    }
    __syncthreads();

    // ---- MFMA main ----
    const float bv = b[c];
    f32x4 acc[4];
    #pragma unroll
    for (int xt = 0; xt < 4; ++xt) acc[xt] = (f32x4){bv, bv, bv, bv};

    const int rowbase = (wr << 4) + r16;
    for (int ky = 0; ky < 9; ++ky) {
        const int row = rowbase + ky;
        const int sx  = (row & 7) << 4;
        const int rb  = row * 160 + (g << 4);
        h16x8 a[4];
        #pragma unroll
        for (int xt = 0; xt < 4; ++xt)
            a[xt] = *(const h16x8*)(lds + ((rb + (xt << 5)) ^ sx));
        const h16x8 bfrag = *(const h16x8*)(lds + O_FRAG_OFF + (ky << 10) + (lane << 4));
        #pragma unroll
        for (int xt = 0; xt < 4; ++xt)
            acc[xt] = __builtin_amdgcn_mfma_f32_16x16x32_f16(a[xt], bfrag, acc[xt], 0, 0, 0);
    }

    // ---- epilogue: direct f32 stores (4x64B segments per instr) ----
    float* op = out + (size_t)plane * HWS;
    #pragma unroll
    for (int xt = 0; xt < 4; ++xt)
        #pragma unroll
        for (int j = 0; j < 4; ++j) {
            const int y = tr + (wr << 4) + (g << 2) + j;
            const int x = tc + (xt << 4) + r16;
            op[(size_t)y * WW + x] = acc[xt][j];
        }
}

// ------------- V transpose per (b,h): vT[d][c] = v[c][d] -------------
__global__ __launch_bounds__(256) void transpose_v(
    const unsigned short* __restrict__ v, unsigned short* __restrict__ vT)
{
    __shared__ unsigned short t[64][72];

    const int bh = blockIdx.z;
    const int c0 = blockIdx.y << 6;
    const int d0 = blockIdx.x << 6;
    const int tid = threadIdx.x;
    const int r  = tid >> 2;
    const int q4 = tid & 3;

    const unsigned short* src = v + (size_t)bh * CC * DD + (size_t)(c0 + r) * DD + d0 + q4 * 16;
    bf16x8 v0 = *(const bf16x8*)(src);
    bf16x8 v1 = *(const bf16x8*)(src + 8);
    #pragma unroll
    for (int e = 0; e < 8; ++e) {
        t[q4 * 16 + e][r]     = (unsigned short)v0[e];
        t[q4 * 16 + 8 + e][r] = (unsigned short)v1[e];
    }
    __syncthreads();

    unsigned short* dst = vT + (size_t)bh * DD * CC + (size_t)(d0 + r) * CC + c0 + q4 * 16;
    *(bf16x8*)dst       = *(const bf16x8*)&t[r][q4 * 16];
    *(bf16x8*)(dst + 8) = *(const bf16x8*)&t[r][q4 * 16 + 8];
}

// ------------- bf16 MFMA GEMM (unchanged) -------------
template<bool IS_QK>
__global__ __launch_bounds__(256) void gemm_bf16(
    const unsigned short* __restrict__ Abuf, const unsigned short* __restrict__ Bbuf,
    void* __restrict__ Dout)
{
    constexpr int KT = IS_QK ? 2048 : 256;
    constexpr int NB = IS_QK ? 256 : 2048;

    __shared__ char lds[24576];

    const int tid = threadIdx.x;
    const int bh  = blockIdx.z;
    const int m0  = blockIdx.y << 7;
    const int n0  = blockIdx.x << 6;

    const unsigned short* Ab = Abuf + (size_t)bh * CC * KT + (size_t)m0 * KT;
    const unsigned short* Bb = Bbuf + (size_t)bh * NB * KT + (size_t)n0 * KT;

    const int lane = tid & 63;
    const int w    = tid >> 6;
    const int wm   = (w >> 1) << 6;
    const int wn   = (w & 1) << 5;
    const int r16  = lane & 15;
    const int g    = lane >> 4;

    const int trow = tid >> 3;
    const int slot = tid & 7;

    f32x4 acc[4][2] = {};

    for (int kt = 0; kt < KT / 64; ++kt) {
        const int kc = kt << 6;
        #pragma unroll
        for (int i = 0; i < 4; ++i) {
            const int row = (i << 5) + trow;
            const int gs  = slot ^ (row & 7);
            const char* srcp = (const char*)(Ab + (size_t)row * KT + kc) + gs * 16;
            GLD_LDS(srcp, lds + (i << 12) + tid * 16);
        }
        #pragma unroll
        for (int i = 0; i < 2; ++i) {
            const int row = (i << 5) + trow;
            const int gs  = slot ^ (row & 7);
            const char* srcp = (const char*)(Bb + (size_t)row * KT + kc) + gs * 16;
            GLD_LDS(srcp, lds + 16384 + (i << 12) + tid * 16);
        }
        __syncthreads();
        #pragma unroll
        for (int kk = 0; kk < 2; ++kk) {
            bf16x8 af[4], bfr[2];
            #pragma unroll
            for (int mi = 0; mi < 4; ++mi) {
                const int row = wm + (mi << 4) + r16;
                af[mi] = *(const bf16x8*)(lds + row * 128 + ((((kk << 2) + g) ^ (row & 7)) << 4));
            }
            #pragma unroll
            for (int nj = 0; nj < 2; ++nj) {
                const int row = wn + (nj << 4) + r16;
                bfr[nj] = *(const bf16x8*)(lds + 16384 + row * 128 + ((((kk << 2) + g) ^ (row & 7)) << 4));
            }
            #pragma unroll
            for (int mi = 0; mi < 4; ++mi)
                #pragma unroll
                for (int nj = 0; nj < 2; ++nj)
                    acc[mi][nj] = __builtin_amdgcn_mfma_f32_16x16x32_bf16(af[mi], bfr[nj], acc[mi][nj], 0, 0, 0);
        }
        __syncthreads();
    }

    if (IS_QK) {
        float* sp = (float*)Dout + (size_t)bh * 65536;
        #pragma unroll
        for (int mi = 0; mi < 4; ++mi)
            #pragma unroll
            for (int nj = 0; nj < 2; ++nj)
                #pragma unroll
                for (int j = 0; j < 4; ++j) {
                    const int row = m0 + wm + (mi << 4) + (g << 2) + j;
                    const int col = n0 + wn + (nj << 4) + r16;
                    sp[(size_t)row * 256 + col] = acc[mi][nj][j] * 0.0078125f;
                }
    } else {
        unsigned short* Ao = (unsigned short*)Dout;
        const int b = bh >> 3, h = bh & 7;
        #pragma unroll
        for (int mi = 0; mi < 4; ++mi)
            #pragma unroll
            for (int nj = 0; nj < 2; ++nj)
                #pragma unroll
                for (int j = 0; j < 4; ++j) {
                    const int row = m0 + wm + (mi << 4) + (g << 2) + j;
                    const int col = n0 + wn + (nj << 4) + r16;
                    Ao[((size_t)b * CC + row) * HWS + h * DD + col] = f2bf(acc[mi][nj][j]);
                }
    }
}

// ------------- row softmax: S fp32 -> P bf16 (unchanged) -------------
__global__ __launch_bounds__(256) void softmax_kernel(
    const float* __restrict__ S, __hip_bfloat16* __restrict__ P)
{
    __shared__ float redm[4], reds[4];
    const int row = blockIdx.x;
    const float* p = S + (size_t)row * 256;
    const int tid = threadIdx.x;
    float vv = p[tid];
    float m = vv;
    #pragma unroll
    for (int o = 32; o; o >>= 1) m = fmaxf(m, __shfl_xor(m, o, 64));
    if ((tid & 63) == 0) redm[tid >> 6] = m;
    __syncthreads();
    m = fmaxf(fmaxf(redm[0], redm[1]), fmaxf(redm[2], redm[3]));
    const float e = expf(vv - m);
    float s = e;
    #pragma unroll
    for (int o = 32; o; o >>= 1) s += __shfl_xor(s, o, 64);
    if ((tid & 63) == 0) reds[tid >> 6] = s;
    __syncthreads();
    s = reds[0] + reds[1] + reds[2] + reds[3];
    P[(size_t)row * 256 + tid] = __float2bfloat16(e / s);
}

extern "C" void kernel_launch(void* const* d_in, const int* in_sizes, int n_in,
                              void* d_out, int out_size, void* d_ws, size_t ws_size,
                              hipStream_t stream)
{
    const float* x  = (const float*)d_in[0];
    const float* qw = (const float*)d_in[1];
    const float* qb = (const float*)d_in[2];
    const float* kw = (const float*)d_in[3];
    const float* kb = (const float*)d_in[4];
    const float* vw = (const float*)d_in[5];
    const float* vb = (const float*)d_in[6];
    const float* ow = (const float*)d_in[7];
    const float* ob = (const float*)d_in[8];
    float* out = (float*)d_out;

    char* wsb = (char*)d_ws;
    float*          pe  = (float*)(wsb + 0);
    __hip_bfloat16* q   = (__hip_bfloat16*)(wsb + 16777216UL);
    __hip_bfloat16* k   = (__hip_bfloat16*)(wsb + 50331648UL);
    float*          S   = (float*)(wsb + 83886080UL);
    __hip_bfloat16* P   = (__hip_bfloat16*)(wsb + 92274688UL);
    __hip_bfloat16* v   = (__hip_bfloat16*)(wsb + 96468992UL);
    __hip_bfloat16* vT  = (__hip_bfloat16*)(wsb + 130023424UL);
    unsigned short* A   = (unsigned short*)(wsb + 0);   // aliases pe+q-half (dead by then)
    // Toeplitz f16 tables alias S (6.9 MB <= 8 MB): dead once conv9qkv completes,
    // before gemm<QK> writes S (stream-ordered).
    unsigned short* wt  = (unsigned short*)(wsb + 83886080UL);

    pe_kernel<<<dim3(CC, 4), 256, 0, stream>>>(pe);
    build_wt<<<dim3(CC, 3), 256, 0, stream>>>(qw, kw, vw, wt);
    conv9qkv<<<dim3(BB * CC * 4), 256, 0, stream>>>(
        x, pe, wt, qb, kb, vb,
        (unsigned short*)q, (unsigned short*)k, (unsigned short*)v);
    gemm_bf16<true><<<dim3(4, 2, 32), 256, 0, stream>>>(
        (const unsigned short*)q, (const unsigned short*)k, (void*)S);
    softmax_kernel<<<dim3(32 * 256), 256, 0, stream>>>(S, P);
    transpose_v<<<dim3(DD / 64, CC / 64, 32), 256, 0, stream>>>(
        (const unsigned short*)v, (unsigned short*)vT);
    gemm_bf16<false><<<dim3(32, 2, 32), 256, 0, stream>>>(
        (const unsigned short*)P, (const unsigned short*)vT, (void*)A);
    conv9o<<<dim3(BB * CC * 4), 256, 0, stream>>>(A, ow, ob, out);
}

// Round 3
// 185.331 us; speedup vs baseline: 1.2236x; 1.0354x over previous
//
#include <hip/hip_runtime.h>
#include <hip/hip_bf16.h>
#include <math.h>

#define BB 4
#define CC 256
#define HH 128
#define WW 128
#define HWS (HH*WW)          // 16384
#define NHEADS 8
#define DD (HWS/NHEADS)      // 2048

typedef __attribute__((ext_vector_type(8))) short bf16x8;
typedef __attribute__((ext_vector_type(4))) float f32x4;
typedef __attribute__((ext_vector_type(2))) __fp16 h16x2;
typedef __attribute__((ext_vector_type(8))) __fp16 h16x8;

#define GLD_LDS(g, l) __builtin_amdgcn_global_load_lds( \
    (const __attribute__((address_space(1))) void*)(g),  \
    (__attribute__((address_space(3))) void*)(l), 16, 0, 0)

static __device__ __forceinline__ unsigned short f2bf(float f) {
    unsigned int u = __float_as_uint(f);
    unsigned int r = (u + 0x7FFFu + ((u >> 16) & 1u)) >> 16;
    return (unsigned short)r;
}
static __device__ __forceinline__ float b2f(unsigned short u) {
    return __uint_as_float((unsigned int)u << 16);
}
static __device__ __forceinline__ unsigned int pk2(float a, float b) {
    union { h16x2 h; unsigned int u; } x;
    x.h = __builtin_amdgcn_cvt_pkrtz(a, b);
    return x.u;
}

// ---- Toeplitz fragment tables for MFMA conv: wt[cv][c][ky][lane][8] f16 ----
// T[m][k] = w[c][ky][k-m] for 0<=k-m<=8 else 0; lane: m=lane&15, k=(lane>>4)*8+e
// (used as the A operand; input is the B operand -> D[m=x][n=y])
__global__ __launch_bounds__(256) void build_wt(
    const float* __restrict__ qw, const float* __restrict__ kw,
    const float* __restrict__ vw, unsigned short* __restrict__ wt)
{
    const int c = blockIdx.x, cv = blockIdx.y;
    const float* w = (cv == 0) ? qw : (cv == 1) ? kw : vw;
    unsigned short* dst = wt + ((size_t)(cv * CC + c) * 9) * 512;
    for (int idx = threadIdx.x; idx < 9 * 512; idx += 256) {
        const int ky   = idx >> 9;
        const int rem  = idx & 511;
        const int lane = rem >> 3, e = rem & 7;
        const int m = lane & 15;
        const int k = ((lane >> 4) << 3) + e;
        const int d = k - m;
        const float v = (d >= 0 && d <= 8) ? w[c * 81 + ky * 9 + d] : 0.0f;
        const __fp16 hv = (__fp16)v;
        unsigned short bits;
        __builtin_memcpy(&bits, &hv, 2);
        dst[idx] = bits;
    }
}

// XCD-chunked c-major swizzle: 4096 blocks, 8 XCDs -> each XCD owns 32 channels;
// all 16 blocks (4 batch x 4 tiles) of a channel are contiguous on one XCD.
static __device__ __forceinline__ void decode_bid(int bid, int& c, int& bidx, int& t) {
    const int u = (bid & 7) * 512 + (bid >> 3);
    c = u >> 4; bidx = (u >> 2) & 3; t = u & 3;
}

// ------- fused QKV depthwise 9x9 conv — MFMA Toeplitz, inline PE, 1 barrier -------
#define TILE_BYTES 11520           // 72 rows * 160 B (80 f16)
#define AWB_OFF    TILE_BYTES      // 27 * 1024 = 27648
#define PE_COEF   (-1.1243088e-3f) // -ln(10000)/8192
#define PE_RSTEP  (0.99887632f)    // exp(PE_COEF)
__global__ __launch_bounds__(256, 4) void conv9qkv(
    const float* __restrict__ in,
    const unsigned short* __restrict__ wt,
    const float* __restrict__ b0, const float* __restrict__ b1,
    const float* __restrict__ b2,
    unsigned short* __restrict__ o0, unsigned short* __restrict__ o1,
    unsigned short* __restrict__ o2)
{
    __shared__ alignas(16) char lds[TILE_BYTES + 27648];   // 39168 B -> 4 blocks/CU

    int c, bidx, t;
    decode_bid(blockIdx.x, c, bidx, t);
    const int plane = bidx * CC + c;
    const int tr    = (t >> 1) << 6;
    const int tc    = (t & 1) << 6;
    const int tid   = threadIdx.x;
    const int lane  = tid & 63;
    const int wr    = tid >> 6;
    const int r16   = lane & 15;
    const int g     = lane >> 4;

    // ---- async staging of the 27 Toeplitz fragments (linear lane*16 layout) ----
    for (int f = wr; f < 27; f += 4) {
        const int cv = f / 9;
        const int ky = f - cv * 9;
        const char* src = (const char*)wt
            + ((((size_t)cv * CC + c) * 9 + ky) << 10) + (lane << 4);
        GLD_LDS(src, lds + AWB_OFF + (f << 10) + (lane << 4));
    }

    const float* xp = in + (size_t)plane * HWS;
    const float cf  = (float)c;

    // ---- stage 72x80 halo tile (x + inline PE) as f16, XOR-swizzled, 8 px/item ----
    #pragma unroll
    for (int it = 0; it < 3; ++it) {
        const int i = tid + (it << 8);
        if (i < 720) {
            const int row = i / 10;
            const int c8  = i - row * 10;
            const int gy  = tr + row - 4;
            const int gx  = tc + (c8 << 3) - 4;
            uint4 wv = make_uint4(0u, 0u, 0u, 0u);
            if (gy >= 0 && gy < HH) {
                const float* xr = xp + gy * WW;
                if (gx >= 0 && gx + 7 < WW) {
                    const float4 a0 = *(const float4*)(xr + gx);
                    const float4 a1 = *(const float4*)(xr + gx + 4);
                    float dt = __expf(PE_COEF * (float)(((gy << 7) + gx) >> 1));
                    float s, cc;
                    __sincosf(cf * dt, &s, &cc);
                    wv.x = pk2(a0.x + s, a0.y + cc);
                    dt *= PE_RSTEP;
                    __sincosf(cf * dt, &s, &cc);
                    wv.y = pk2(a0.z + s, a0.w + cc);
                    dt *= PE_RSTEP;
                    __sincosf(cf * dt, &s, &cc);
                    wv.z = pk2(a1.x + s, a1.y + cc);
                    dt *= PE_RSTEP;
                    __sincosf(cf * dt, &s, &cc);
                    wv.w = pk2(a1.z + s, a1.w + cc);
                } else {
                    float vv[8];
                    #pragma unroll
                    for (int e = 0; e < 8; ++e) {
                        const int gxe = gx + e;
                        float xv = 0.f;
                        if (gxe >= 0 && gxe < WW) {
                            const int flat = (gy << 7) + gxe;
                            const float dt = __expf(PE_COEF * (float)(flat >> 1));
                            float s, cc;
                            __sincosf(cf * dt, &s, &cc);
                            xv = xr[gxe] + ((flat & 1) ? cc : s);
                        }
                        vv[e] = xv;
                    }
                    wv.x = pk2(vv[0], vv[1]); wv.y = pk2(vv[2], vv[3]);
                    wv.z = pk2(vv[4], vv[5]); wv.w = pk2(vv[6], vv[7]);
                }
            }
            int byte = row * 160 + (c8 << 4);
            byte ^= (row & 7) << 4;
            *(uint4*)(lds + byte) = wv;
        }
    }
    __syncthreads();

    // ---- MFMA main: D[m=x][n=y] += T[m][k=x'] * In[k=x'][n=y], per ky ----
    f32x4 acc[3][4];
    {
        const float bq = b0[c], bk = b1[c], bv = b2[c];
        #pragma unroll
        for (int xt = 0; xt < 4; ++xt) {
            acc[0][xt] = (f32x4){bq, bq, bq, bq};
            acc[1][xt] = (f32x4){bk, bk, bk, bk};
            acc[2][xt] = (f32x4){bv, bv, bv, bv};
        }
    }

    const int rowbase = (wr << 4) + r16;
    for (int ky = 0; ky < 9; ++ky) {
        const int row = rowbase + ky;
        const int sx  = (row & 7) << 4;
        const int rb  = row * 160 + (g << 4);
        h16x8 a[4];
        #pragma unroll
        for (int xt = 0; xt < 4; ++xt)
            a[xt] = *(const h16x8*)(lds + ((rb + (xt << 5)) ^ sx));
        #pragma unroll
        for (int cv = 0; cv < 3; ++cv) {
            const h16x8 tf = *(const h16x8*)(lds + AWB_OFF + ((cv * 9 + ky) << 10) + (lane << 4));
            #pragma unroll
            for (int xt = 0; xt < 4; ++xt)
                acc[cv][xt] = __builtin_amdgcn_mfma_f32_16x16x32_f16(
                    tf, a[xt], acc[cv][xt], 0, 0, 0);
        }
    }

    // ---- epilogue: direct packed stores (lane holds 4 consecutive x at row y=r16) ----
    unsigned short* const outs[3] = { o0, o1, o2 };
    const int y  = tr + (wr << 4) + r16;
    const int hh = y >> 4;
    const size_t base = (((size_t)(bidx * NHEADS + hh) * CC + c) << 11)
                      + ((size_t)(y & 15) << 7) + tc + (g << 2);
    #pragma unroll
    for (int cv = 0; cv < 3; ++cv)
        #pragma unroll
        for (int xt = 0; xt < 4; ++xt) {
            ushort4 u;
            u.x = f2bf(acc[cv][xt][0]); u.y = f2bf(acc[cv][xt][1]);
            u.z = f2bf(acc[cv][xt][2]); u.w = f2bf(acc[cv][xt][3]);
            *(ushort4*)(outs[cv] + base + (xt << 4)) = u;
        }
}

// ------- output depthwise 9x9 conv: bf16 input, MFMA Toeplitz, direct f32x4 stores -------
#define O_FRAG_OFF 11520           // 9 * 1024 = 9216 bytes of fragments
__global__ __launch_bounds__(256, 4) void conv9o(
    const unsigned short* __restrict__ ain,
    const float* __restrict__ w, const float* __restrict__ b,
    float* __restrict__ out)
{
    __shared__ alignas(16) char lds[O_FRAG_OFF + 9216];
    __shared__ float lw[81];

    int c, bidx, t;
    decode_bid(blockIdx.x, c, bidx, t);
    const int plane = bidx * CC + c;
    const int tr    = (t >> 1) << 6;
    const int tc    = (t & 1) << 6;
    const int tid   = threadIdx.x;
    const int lane  = tid & 63;
    const int wr    = tid >> 6;
    const int r16   = lane & 15;
    const int g     = lane >> 4;

    if (tid < 81) lw[tid] = w[c * 81 + tid];

    const unsigned short* ap = ain + (size_t)plane * HWS;

    // ---- stage 72x80 halo tile as f16, XOR-swizzled, 8 px / item ----
    #pragma unroll
    for (int it = 0; it < 3; ++it) {
        const int i = tid + (it << 8);
        if (i < 720) {
            const int row = i / 10;
            const int c8  = i - row * 10;
            const int gy  = tr + row - 4;
            const int gx  = tc + (c8 << 3) - 4;
            uint4 wv = make_uint4(0u, 0u, 0u, 0u);
            if (gy >= 0 && gy < HH) {
                const unsigned short* ar = ap + gy * WW;
                if (gx >= 0 && gx + 7 < WW) {
                    const bf16x8 u = *(const bf16x8*)(ar + gx);
                    wv.x = pk2(b2f((unsigned short)u[0]), b2f((unsigned short)u[1]));
                    wv.y = pk2(b2f((unsigned short)u[2]), b2f((unsigned short)u[3]));
                    wv.z = pk2(b2f((unsigned short)u[4]), b2f((unsigned short)u[5]));
                    wv.w = pk2(b2f((unsigned short)u[6]), b2f((unsigned short)u[7]));
                } else {
                    float vv[8];
                    #pragma unroll
                    for (int e = 0; e < 8; ++e) {
                        const int gxe = gx + e;
                        vv[e] = (gxe >= 0 && gxe < WW) ? b2f(ar[gxe]) : 0.f;
                    }
                    wv.x = pk2(vv[0], vv[1]); wv.y = pk2(vv[2], vv[3]);
                    wv.z = pk2(vv[4], vv[5]); wv.w = pk2(vv[6], vv[7]);
                }
            }
            int byte = row * 160 + (c8 << 4);
            byte ^= (row & 7) << 4;
            *(uint4*)(lds + byte) = wv;
        }
    }
    __syncthreads();

    // ---- build the 9 Toeplitz fragments in LDS from lw (u32 = f16 pair per write) ----
    {
        const int ln = tid >> 2, qq = tid & 3;
        const int m  = ln & 15;
        const int k0 = ((ln >> 4) << 3) + (qq << 1);
        const int d0 = k0 - m, d1 = k0 + 1 - m;
        #pragma unroll
        for (int ky = 0; ky < 9; ++ky) {
            const float f0 = (d0 >= 0 && d0 <= 8) ? lw[ky * 9 + d0] : 0.f;
            const float f1 = (d1 >= 0 && d1 <= 8) ? lw[ky * 9 + d1] : 0.f;
            *(unsigned int*)(lds + O_FRAG_OFF + (ky << 10) + (ln << 4) + (qq << 2)) = pk2(f0, f1);
        }
    }
    __syncthreads();

    // ---- MFMA main (Toeplitz as A operand -> lane holds 4 consecutive x) ----
    const float bv = b[c];
    f32x4 acc[4];
    #pragma unroll
    for (int xt = 0; xt < 4; ++xt) acc[xt] = (f32x4){bv, bv, bv, bv};

    const int rowbase = (wr << 4) + r16;
    for (int ky = 0; ky < 9; ++ky) {
        const int row = rowbase + ky;
        const int sx  = (row & 7) << 4;
        const int rb  = row * 160 + (g << 4);
        h16x8 a[4];
        #pragma unroll
        for (int xt = 0; xt < 4; ++xt)
            a[xt] = *(const h16x8*)(lds + ((rb + (xt << 5)) ^ sx));
        const h16x8 tf = *(const h16x8*)(lds + O_FRAG_OFF + (ky << 10) + (lane << 4));
        #pragma unroll
        for (int xt = 0; xt < 4; ++xt)
            acc[xt] = __builtin_amdgcn_mfma_f32_16x16x32_f16(tf, a[xt], acc[xt], 0, 0, 0);
    }

    // ---- epilogue: direct float4 stores (64B contiguous per row) ----
    const int y = tr + (wr << 4) + r16;
    float* orow = out + (size_t)plane * HWS + (size_t)y * WW + tc + (g << 2);
    #pragma unroll
    for (int xt = 0; xt < 4; ++xt)
        *(f32x4*)(orow + (xt << 4)) = acc[xt];
}

// ------------- V transpose per (b,h): vT[d][c] = v[c][d] -------------
__global__ __launch_bounds__(256) void transpose_v(
    const unsigned short* __restrict__ v, unsigned short* __restrict__ vT)
{
    __shared__ unsigned short t[64][72];

    const int bh = blockIdx.z;
    const int c0 = blockIdx.y << 6;
    const int d0 = blockIdx.x << 6;
    const int tid = threadIdx.x;
    const int r  = tid >> 2;
    const int q4 = tid & 3;

    const unsigned short* src = v + (size_t)bh * CC * DD + (size_t)(c0 + r) * DD + d0 + q4 * 16;
    bf16x8 v0 = *(const bf16x8*)(src);
    bf16x8 v1 = *(const bf16x8*)(src + 8);
    #pragma unroll
    for (int e = 0; e < 8; ++e) {
        t[q4 * 16 + e][r]     = (unsigned short)v0[e];
        t[q4 * 16 + 8 + e][r] = (unsigned short)v1[e];
    }
    __syncthreads();

    unsigned short* dst = vT + (size_t)bh * DD * CC + (size_t)(d0 + r) * CC + c0 + q4 * 16;
    *(bf16x8*)dst       = *(const bf16x8*)&t[r][q4 * 16];
    *(bf16x8*)(dst + 8) = *(const bf16x8*)&t[r][q4 * 16 + 8];
}

// ------------- bf16 MFMA GEMM (unchanged) -------------
template<bool IS_QK>
__global__ __launch_bounds__(256) void gemm_bf16(
    const unsigned short* __restrict__ Abuf, const unsigned short* __restrict__ Bbuf,
    void* __restrict__ Dout)
{
    constexpr int KT = IS_QK ? 2048 : 256;
    constexpr int NB = IS_QK ? 256 : 2048;

    __shared__ char lds[24576];

    const int tid = threadIdx.x;
    const int bh  = blockIdx.z;
    const int m0  = blockIdx.y << 7;
    const int n0  = blockIdx.x << 6;

    const unsigned short* Ab = Abuf + (size_t)bh * CC * KT + (size_t)m0 * KT;
    const unsigned short* Bb = Bbuf + (size_t)bh * NB * KT + (size_t)n0 * KT;

    const int lane = tid & 63;
    const int w    = tid >> 6;
    const int wm   = (w >> 1) << 6;
    const int wn   = (w & 1) << 5;
    const int r16  = lane & 15;
    const int g    = lane >> 4;

    const int trow = tid >> 3;
    const int slot = tid & 7;

    f32x4 acc[4][2] = {};

    for (int kt = 0; kt < KT / 64; ++kt) {
        const int kc = kt << 6;
        #pragma unroll
        for (int i = 0; i < 4; ++i) {
            const int row = (i << 5) + trow;
            const int gs  = slot ^ (row & 7);
            const char* srcp = (const char*)(Ab + (size_t)row * KT + kc) + gs * 16;
            GLD_LDS(srcp, lds + (i << 12) + tid * 16);
        }
        #pragma unroll
        for (int i = 0; i < 2; ++i) {
            const int row = (i << 5) + trow;
            const int gs  = slot ^ (row & 7);
            const char* srcp = (const char*)(Bb + (size_t)row * KT + kc) + gs * 16;
            GLD_LDS(srcp, lds + 16384 + (i << 12) + tid * 16);
        }
        __syncthreads();
        #pragma unroll
        for (int kk = 0; kk < 2; ++kk) {
            bf16x8 af[4], bfr[2];
            #pragma unroll
            for (int mi = 0; mi < 4; ++mi) {
                const int row = wm + (mi << 4) + r16;
                af[mi] = *(const bf16x8*)(lds + row * 128 + ((((kk << 2) + g) ^ (row & 7)) << 4));
            }
            #pragma unroll
            for (int nj = 0; nj < 2; ++nj) {
                const int row = wn + (nj << 4) + r16;
                bfr[nj] = *(const bf16x8*)(lds + 16384 + row * 128 + ((((kk << 2) + g) ^ (row & 7)) << 4));
            }
            #pragma unroll
            for (int mi = 0; mi < 4; ++mi)
                #pragma unroll
                for (int nj = 0; nj < 2; ++nj)
                    acc[mi][nj] = __builtin_amdgcn_mfma_f32_16x16x32_bf16(af[mi], bfr[nj], acc[mi][nj], 0, 0, 0);
        }
        __syncthreads();
    }

    if (IS_QK) {
        float* sp = (float*)Dout + (size_t)bh * 65536;
        #pragma unroll
        for (int mi = 0; mi < 4; ++mi)
            #pragma unroll
            for (int nj = 0; nj < 2; ++nj)
                #pragma unroll
                for (int j = 0; j < 4; ++j) {
                    const int row = m0 + wm + (mi << 4) + (g << 2) + j;
                    const int col = n0 + wn + (nj << 4) + r16;
                    sp[(size_t)row * 256 + col] = acc[mi][nj][j] * 0.0078125f;
                }
    } else {
        unsigned short* Ao = (unsigned short*)Dout;
        const int b = bh >> 3, h = bh & 7;
        #pragma unroll
        for (int mi = 0; mi < 4; ++mi)
            #pragma unroll
            for (int nj = 0; nj < 2; ++nj)
                #pragma unroll
                for (int j = 0; j < 4; ++j) {
                    const int row = m0 + wm + (mi << 4) + (g << 2) + j;
                    const int col = n0 + wn + (nj << 4) + r16;
                    Ao[((size_t)b * CC + row) * HWS + h * DD + col] = f2bf(acc[mi][nj][j]);
                }
    }
}

// ------------- row softmax: S fp32 -> P bf16 (unchanged) -------------
__global__ __launch_bounds__(256) void softmax_kernel(
    const float* __restrict__ S, __hip_bfloat16* __restrict__ P)
{
    __shared__ float redm[4], reds[4];
    const int row = blockIdx.x;
    const float* p = S + (size_t)row * 256;
    const int tid = threadIdx.x;
    float vv = p[tid];
    float m = vv;
    #pragma unroll
    for (int o = 32; o; o >>= 1) m = fmaxf(m, __shfl_xor(m, o, 64));
    if ((tid & 63) == 0) redm[tid >> 6] = m;
    __syncthreads();
    m = fmaxf(fmaxf(redm[0], redm[1]), fmaxf(redm[2], redm[3]));
    const float e = expf(vv - m);
    float s = e;
    #pragma unroll
    for (int o = 32; o; o >>= 1) s += __shfl_xor(s, o, 64);
    if ((tid & 63) == 0) reds[tid >> 6] = s;
    __syncthreads();
    s = reds[0] + reds[1] + reds[2] + reds[3];
    P[(size_t)row * 256 + tid] = __float2bfloat16(e / s);
}

extern "C" void kernel_launch(void* const* d_in, const int* in_sizes, int n_in,
                              void* d_out, int out_size, void* d_ws, size_t ws_size,
                              hipStream_t stream)
{
    const float* x  = (const float*)d_in[0];
    const float* qw = (const float*)d_in[1];
    const float* qb = (const float*)d_in[2];
    const float* kw = (const float*)d_in[3];
    const float* kb = (const float*)d_in[4];
    const float* vw = (const float*)d_in[5];
    const float* vb = (const float*)d_in[6];
    const float* ow = (const float*)d_in[7];
    const float* ob = (const float*)d_in[8];
    float* out = (float*)d_out;

    char* wsb = (char*)d_ws;
    __hip_bfloat16* q   = (__hip_bfloat16*)(wsb + 16777216UL);
    __hip_bfloat16* k   = (__hip_bfloat16*)(wsb + 50331648UL);
    float*          S   = (float*)(wsb + 83886080UL);
    __hip_bfloat16* P   = (__hip_bfloat16*)(wsb + 92274688UL);
    __hip_bfloat16* v   = (__hip_bfloat16*)(wsb + 96468992UL);
    __hip_bfloat16* vT  = (__hip_bfloat16*)(wsb + 130023424UL);
    unsigned short* A   = (unsigned short*)(wsb + 0);   // dead region by PV time
    // Toeplitz f16 tables alias S (6.9 MB <= 8 MB): consumed by conv9qkv before
    // gemm<QK> writes S (stream-ordered).
    unsigned short* wt  = (unsigned short*)(wsb + 83886080UL);

    build_wt<<<dim3(CC, 3), 256, 0, stream>>>(qw, kw, vw, wt);
    conv9qkv<<<dim3(BB * CC * 4), 256, 0, stream>>>(
        x, wt, qb, kb, vb,
        (unsigned short*)q, (unsigned short*)k, (unsigned short*)v);
    gemm_bf16<true><<<dim3(4, 2, 32), 256, 0, stream>>>(
        (const unsigned short*)q, (const unsigned short*)k, (void*)S);
    softmax_kernel<<<dim3(32 * 256), 256, 0, stream>>>(S, P);
    transpose_v<<<dim3(DD / 64, CC / 64, 32), 256, 0, stream>>>(
        (const unsigned short*)v, (unsigned short*)vT);
    gemm_bf16<false><<<dim3(32, 2, 32), 256, 0, stream>>>(
        (const unsigned short*)P, (const unsigned short*)vT, (void*)A);
    conv9o<<<dim3(BB * CC * 4), 256, 0, stream>>>(A, ow, ob, out);
}